// Round 4
// baseline (594.113 us; speedup 1.0000x reference)
//
#include <hip/hip_runtime.h>
#include <cstddef>

// Exact IEEE f32 per-op (top-k ranking + sampling paths match numpy f32
// bit-for-bit; absmax was 0.0 in rounds 2-3). Explicit fmaf() unaffected.
#pragma clang fp contract(off)

// ---------- bilinear sample plan, ref-exact f32 arithmetic ----------
struct Samp {
    int o00, o01, o10, o11;      // linear offset y*128+x, -1 if invalid (zero pad)
    float w00, w01, w10, w11;
};
__device__ __forceinline__ float grid_coord(float p) {
    float g = 2.0f * p - 1.0f;
    return ((g + 1.0f) * 128.0f - 1.0f) * 0.5f;
}
__device__ __forceinline__ Samp mk_samp(float px, float py) {
    Samp s;
    float gx = grid_coord(px);
    float gy = grid_coord(py);
    float x0f = floorf(gx), y0f = floorf(gy);
    float wx1 = gx - x0f, wy1 = gy - y0f;
    float wx0 = 1.0f - wx1, wy0 = 1.0f - wy1;
    int x0 = (int)x0f, y0 = (int)y0f;
    int x1 = x0 + 1, y1 = y0 + 1;
    bool vx0 = (x0 >= 0) && (x0 < 128);
    bool vx1 = (x1 >= 0) && (x1 < 128);
    bool vy0 = (y0 >= 0) && (y0 < 128);
    bool vy1 = (y1 >= 0) && (y1 < 128);
    s.o00 = (vx0 && vy0) ? (y0 * 128 + x0) : -1;
    s.o01 = (vx1 && vy0) ? (y0 * 128 + x1) : -1;
    s.o10 = (vx0 && vy1) ? (y1 * 128 + x0) : -1;
    s.o11 = (vx1 && vy1) ? (y1 * 128 + x1) : -1;
    s.w00 = wx0 * wy0; s.w01 = wx1 * wy0;
    s.w10 = wx0 * wy1; s.w11 = wx1 * wy1;
    return s;
}
__device__ __forceinline__ float samp_apply(const float* __restrict__ img, const Samp& s) {
    float v00 = (s.o00 >= 0) ? img[s.o00] : 0.f;
    float v01 = (s.o01 >= 0) ? img[s.o01] : 0.f;
    float v10 = (s.o10 >= 0) ? img[s.o10] : 0.f;
    float v11 = (s.o11 >= 0) ? img[s.o11] : 0.f;
    return ((s.w00 * v00 + s.w01 * v01) + s.w10 * v10) + s.w11 * v11;
}
__device__ __forceinline__ float gelu_exact(float h) {
    return 0.5f * h * (1.f + erff(h * 0.70710678118654752f));
}

// ---------- kernel 1: sampling points + coarse (UNCHANGED from passing run) ----------
__global__ __launch_bounds__(384) void k_points(
    const float* __restrict__ out, const float* __restrict__ over_gen,
    const float* __restrict__ rand_point,
    float* __restrict__ d_out, float* __restrict__ pts_ws, float* __restrict__ coarse_ws)
{
    int b = blockIdx.x;
    int tid = threadIdx.x;
    __shared__ float unc[384];
    __shared__ float pts[128][2];
    size_t outbase = (size_t)b * 2 * 16384;
    float px = over_gen[(size_t)(b * 384 + tid) * 2 + 0];
    float py = over_gen[(size_t)(b * 384 + tid) * 2 + 1];
    {
        Samp s = mk_samp(px, py);
        float M00 = 0.f, M01 = 0.f, M10 = 0.f, M11 = 0.f;
        float m00 = 0.f, m01 = 0.f, m10 = 0.f, m11 = 0.f;
        if (s.o00 >= 0) { float a = out[outbase + s.o00], c = out[outbase + 16384 + s.o00]; M00 = fmaxf(a, c); m00 = fminf(a, c); }
        if (s.o01 >= 0) { float a = out[outbase + s.o01], c = out[outbase + 16384 + s.o01]; M01 = fmaxf(a, c); m01 = fminf(a, c); }
        if (s.o10 >= 0) { float a = out[outbase + s.o10], c = out[outbase + 16384 + s.o10]; M10 = fmaxf(a, c); m10 = fminf(a, c); }
        if (s.o11 >= 0) { float a = out[outbase + s.o11], c = out[outbase + 16384 + s.o11]; M11 = fmaxf(a, c); m11 = fminf(a, c); }
        float og0 = ((s.w00 * M00 + s.w01 * M01) + s.w10 * M10) + s.w11 * M11;
        float og1 = ((s.w00 * m00 + s.w01 * m01) + s.w10 * m10) + s.w11 * m11;
        unc[tid] = og1 - og0;
    }
    __syncthreads();
    {   // exact lax.top_k(96): value desc, tie -> lower index
        float v = unc[tid];
        int rank = 0;
        for (int j = 0; j < 384; ++j) {
            float u = unc[j];
            rank += (u > v) || (u == v && j < tid);
        }
        if (rank < 96) { pts[rank][0] = px; pts[rank][1] = py; }
    }
    if (tid < 16) {          // coverage rows: zeros (dead sobel path)
        pts[96 + tid][0] = 0.f; pts[96 + tid][1] = 0.f;
    } else if (tid < 32) {   // random tail
        int r = tid - 16;
        pts[112 + r][0] = rand_point[(size_t)(b * 16 + r) * 2 + 0];
        pts[112 + r][1] = rand_point[(size_t)(b * 16 + r) * 2 + 1];
    }
    __syncthreads();
    if (tid < 128) {
        float qx = pts[tid][0], qy = pts[tid][1];
        pts_ws[(b * 128 + tid) * 2 + 0] = qx;
        pts_ws[(b * 128 + tid) * 2 + 1] = qy;
        d_out[2048 + (size_t)(b * 128 + tid) * 2 + 0] = qx;
        d_out[2048 + (size_t)(b * 128 + tid) * 2 + 1] = qy;
    }
    if (tid < 256) {
        int c = tid >> 7, n = tid & 127;
        Samp s = mk_samp(pts[n][0], pts[n][1]);
        coarse_ws[(b * 2 + c) * 128 + n] = samp_apply(out + (size_t)(b * 2 + c) * 16384, s);
    }
}

// ---------- kernel 2: build inverted pixel -> (point,neighbor) chains ----------
// entry e = n*4+nb (no dedup needed; duplicate pixels chain via nxt).
__global__ __launch_bounds__(512) void k_slots(
    const float* __restrict__ pts_ws, float* __restrict__ wgt4,
    int* __restrict__ head, int* __restrict__ nxt)
{
    int b = blockIdx.x, tid = threadIdx.x;
    int4* h4 = (int4*)(head + b * 16384);
    int4 m1; m1.x = m1.y = m1.z = m1.w = -1;
    for (int i = tid; i < 4096; i += 512) h4[i] = m1;
    __syncthreads();
    int n = tid >> 2, nb = tid & 3;
    float px = pts_ws[(b * 128 + n) * 2 + 0];
    float py = pts_ws[(b * 128 + n) * 2 + 1];
    Samp s = mk_samp(px, py);
    int   o = (nb == 0) ? s.o00 : (nb == 1) ? s.o01 : (nb == 2) ? s.o10 : s.o11;
    float w = (nb == 0) ? s.w00 : (nb == 1) ? s.w01 : (nb == 2) ? s.w10 : s.w11;
    wgt4[(b * 128 + n) * 4 + nb] = (o >= 0) ? w : 0.0f;   // 0-weight gates unwritten cols
    if (o >= 0) nxt[b * 512 + tid] = atomicExch(&head[b * 16384 + o], tid);
}

// ---------- kernel 3: coalesced full stream of res2, scatter needed pixels ----------
// Scattered line-gather measured only 428 GB/s (R3); full coalesced stream of
// the 256 MB runs at ~6 TB/s. asm-consume pins the load (compiler must not
// sink it under the ~3% hit condition, which would recreate the slow pattern).
__global__ __launch_bounds__(256) void k_stream(
    const float* __restrict__ res2, const int* __restrict__ head,
    const int* __restrict__ nxt, float* __restrict__ cols)
{
    size_t t = (size_t)blockIdx.x * 256 + threadIdx.x;   // one float4 each; 16,777,216 total
    int q  = (int)(t & 4095);        // quad index within 128x128 image
    int bc = (int)(t >> 12);         // b*512 + ch
    int b  = bc >> 9;
    int ch = bc & 511;
    const int4 h4 = ((const int4*)(head + b * 16384))[q];
    float4 v = ((const float4*)res2)[t];
    asm volatile("" :: "v"(v.x), "v"(v.y), "v"(v.z), "v"(v.w));  // force the coalesced load
    float* colb = cols + ((size_t)b << 18) + ch;
    const int* nx = nxt + (b << 9);
    int e;
    e = h4.x; while (e >= 0) { colb[(size_t)e << 9] = v.x; e = nx[e]; }
    e = h4.y; while (e >= 0) { colb[(size_t)e << 9] = v.y; e = nx[e]; }
    e = h4.z; while (e >= 0) { colb[(size_t)e << 9] = v.z; e = nx[e]; }
    e = h4.w; while (e >= 0) { colb[(size_t)e << 9] = v.w; e = nx[e]; }
}

// ---------- kernel 4: MLP (phases B/C/D verbatim from passing kernel) ----------
#define ROWS 4
__global__ __launch_bounds__(512) void k_mlp(
    const float* __restrict__ cols, const float* __restrict__ wgt4,
    const float* __restrict__ coarse_ws,
    const float* __restrict__ w1, const float* __restrict__ b1,
    const float* __restrict__ g1, const float* __restrict__ be1,
    const float* __restrict__ w2, const float* __restrict__ b2,
    const float* __restrict__ g2, const float* __restrict__ be2,
    const float* __restrict__ w3, const float* __restrict__ b3,
    const float* __restrict__ mask, float* __restrict__ d_out)
{
    __shared__ float feat[ROWS][514];
    __shared__ float h1s[ROWS][512];
    __shared__ float h2s[ROWS][256];
    __shared__ float part2[256][ROWS];
    __shared__ float pd[8][32];
    __shared__ float red_s[8][ROWS], red_q[8][ROWS];
    __shared__ float stat_m[ROWS], stat_r[ROWS];

    int blk = blockIdx.x;
    int b = blk >> 5, n0 = (blk & 31) * ROWS;
    int tid = threadIdx.x;
    int wave = tid >> 6, lane = tid & 63;

    if (tid < ROWS * 2) {   // coarse -> feat[r][0:2]
        int r = tid >> 1, c = tid & 1;
        feat[r][c] = coarse_ws[(b * 2 + c) * 128 + (n0 + r)];
    }
    // ---- Phase A': weighted sum of L2-resident cols (ref-exact order) ----
#pragma unroll
    for (int r = 0; r < ROWS; ++r) {
        const float4 wg = ((const float4*)wgt4)[b * 128 + n0 + r];
        const float* basep = cols + ((size_t)b << 18) + (size_t)((n0 + r) * 4) * 512 + tid;
        float v00 = basep[0], v01 = basep[512], v10 = basep[1024], v11 = basep[1536];
        feat[r][2 + tid] = ((wg.x * v00 + wg.y * v01) + wg.z * v10) + wg.w * v11;
    }
    __syncthreads();

    // ---- Phase B: feat @ w1 + b1 -> LN -> gelu -> h1s ----
    int col = tid;
    float acc1[ROWS] = {0.f, 0.f, 0.f, 0.f};
    for (int k = 0; k < 514; ++k) {
        float w = w1[(size_t)k * 512 + col];
#pragma unroll
        for (int r = 0; r < ROWS; ++r) acc1[r] = fmaf(feat[r][k], w, acc1[r]);
    }
    {
        float bb = b1[col], ga = g1[col], ea = be1[col];
        float v[ROWS];
#pragma unroll
        for (int r = 0; r < ROWS; ++r) v[r] = acc1[r] + bb;
#pragma unroll
        for (int r = 0; r < ROWS; ++r) {
            float s = v[r], q = v[r] * v[r];
            for (int off = 32; off > 0; off >>= 1) {
                s += __shfl_down(s, off, 64);
                q += __shfl_down(q, off, 64);
            }
            if (lane == 0) { red_s[wave][r] = s; red_q[wave][r] = q; }
        }
        __syncthreads();
        if (tid < ROWS) {
            float s = 0.f, q = 0.f;
            for (int w8 = 0; w8 < 8; ++w8) { s += red_s[w8][tid]; q += red_q[w8][tid]; }
            float m = s * (1.f / 512.f);
            float var = q * (1.f / 512.f) - m * m;
            stat_m[tid] = m;
            stat_r[tid] = 1.f / sqrtf(var + 1e-5f);
        }
        __syncthreads();
#pragma unroll
        for (int r = 0; r < ROWS; ++r)
            h1s[r][col] = gelu_exact((v[r] - stat_m[r]) * stat_r[r] * ga + ea);
    }
    __syncthreads();

    // ---- Phase C: h1 @ w2 + b2 -> LN -> gelu -> h2s  (split-k x2) ----
    int c2 = tid & 255, kh = tid >> 8;
    float acc2[ROWS] = {0.f, 0.f, 0.f, 0.f};
    for (int k = 0; k < 256; ++k) {
        int kk = (kh << 8) + k;
        float w = w2[(size_t)kk * 256 + c2];
#pragma unroll
        for (int r = 0; r < ROWS; ++r) acc2[r] = fmaf(h1s[r][kk], w, acc2[r]);
    }
    if (kh == 1) {
#pragma unroll
        for (int r = 0; r < ROWS; ++r) part2[c2][r] = acc2[r];
    }
    __syncthreads();
    float v2[ROWS];
    float ga2 = 0.f, ea2 = 0.f;
    if (kh == 0) {
        float bb2 = b2[c2];
        ga2 = g2[c2]; ea2 = be2[c2];
#pragma unroll
        for (int r = 0; r < ROWS; ++r) {
            v2[r] = (acc2[r] + part2[c2][r]) + bb2;
            float s = v2[r], q = v2[r] * v2[r];
            for (int off = 32; off > 0; off >>= 1) {
                s += __shfl_down(s, off, 64);
                q += __shfl_down(q, off, 64);
            }
            if (lane == 0) { red_s[wave][r] = s; red_q[wave][r] = q; }
        }
    }
    __syncthreads();
    if (tid < ROWS) {
        float s = 0.f, q = 0.f;
        for (int w4 = 0; w4 < 4; ++w4) { s += red_s[w4][tid]; q += red_q[w4][tid]; }
        float m = s * (1.f / 256.f);
        float var = q * (1.f / 256.f) - m * m;
        stat_m[tid] = m;
        stat_r[tid] = 1.f / sqrtf(var + 1e-5f);
    }
    __syncthreads();
    if (kh == 0) {
#pragma unroll
        for (int r = 0; r < ROWS; ++r)
            h2s[r][c2] = gelu_exact((v2[r] - stat_m[r]) * stat_r[r] * ga2 + ea2);
    }
    __syncthreads();

    // ---- Phase D: h2 @ w3 + b3, dropout-mask, + coarse -> rend ----
    if (tid < 256) {
        int rc = tid >> 5, l = tid & 31;
        int r = rc >> 1, c = rc & 1;
        float p = 0.f;
        for (int k = l; k < 256; k += 32) p = fmaf(h2s[r][k], w3[k * 2 + c], p);
        pd[rc][l] = p;
    }
    __syncthreads();
    if (tid < 8) {
        int r = tid >> 1, c = tid & 1;
        float acc = 0.f;
        for (int l = 0; l < 32; ++l) acc += pd[tid][l];
        float pred = acc + b3[c];
        int oi = b * 256 + c * 128 + (n0 + r);
        d_out[oi] = pred * mask[oi] + coarse_ws[oi];
    }
}

extern "C" void kernel_launch(void* const* d_in, const int* in_sizes, int n_in,
                              void* d_out, int out_size, void* d_ws, size_t ws_size,
                              hipStream_t stream) {
    const float* res2 = (const float*)d_in[1];
    const float* out  = (const float*)d_in[2];
    const float* over_gen   = (const float*)d_in[3];
    const float* rand_point = (const float*)d_in[4];
    const float* mask = (const float*)d_in[5];
    const float* w1 = (const float*)d_in[6];
    const float* b1 = (const float*)d_in[7];
    const float* g1 = (const float*)d_in[8];
    const float* be1 = (const float*)d_in[9];
    const float* w2 = (const float*)d_in[10];
    const float* b2 = (const float*)d_in[11];
    const float* g2 = (const float*)d_in[12];
    const float* be2 = (const float*)d_in[13];
    const float* w3 = (const float*)d_in[14];
    const float* b3 = (const float*)d_in[15];
    float* o = (float*)d_out;  // rend[0:2048], points[2048:4096]

    float* fws = (float*)d_ws;
    float* pts_ws    = fws;                    // 2048 floats
    float* coarse_ws = pts_ws + 2048;          // 2048
    float* wgt4      = coarse_ws + 2048;       // 4096 (float4-aligned)
    float* cols      = wgt4 + 4096;            // 8*512*512 = 2,097,152
    int*   head      = (int*)(cols + (8 << 18));  // 8*16384 = 131,072 ints
    int*   nxt       = head + 8 * 16384;          // 8*512 ints

    k_points<<<8, 384, 0, stream>>>(out, over_gen, rand_point, o, pts_ws, coarse_ws);
    k_slots<<<8, 512, 0, stream>>>(pts_ws, wgt4, head, nxt);
    k_stream<<<65536, 256, 0, stream>>>(res2, head, nxt, cols);
    k_mlp<<<256, 512, 0, stream>>>(cols, wgt4, coarse_ws,
                                   w1, b1, g1, be1, w2, b2, g2, be2, w3, b3,
                                   mask, o);
}